// Round 3
// baseline (662.142 us; speedup 1.0000x reference)
//
#include <hip/hip_runtime.h>

#define UNITS 512
#define EMBD  256
#define BATCH 64
#define TLEN  2048

typedef __bf16 bf16x8 __attribute__((ext_vector_type(8)));
typedef float  f32x4  __attribute__((ext_vector_type(4)));

__device__ __forceinline__ unsigned short f2bf(float x) {
  return __builtin_bit_cast(unsigned short, (__bf16)x);
}
__device__ __forceinline__ float bf2f(unsigned short u) {
  unsigned v = ((unsigned)u) << 16;
  return __builtin_bit_cast(float, v);
}
__device__ __forceinline__ float fast_tanh(float x) {
  float e = __expf(2.0f * x);
  return __fdividef(e - 1.0f, e + 1.0f);
}
__device__ __forceinline__ float fast_sigmoid(float x) {
  return __fdividef(1.0f, 1.0f + __expf(-x));
}

// ---------------------------------------------------------------------------
// relayout: B (K x N f32, row-major) -> MFMA B-fragment order bf16:
//   BF[((ks*NT + nt)*64 + l)*8 + j] = bf16( B[ks*32 + (l>>4)*8 + j][nt*16 + (l&15)] )
// NT = N/16. Optionally zeros gO/gL (pass on exactly one launch).
// ---------------------------------------------------------------------------
__global__ void relayout_kernel(const float* __restrict__ B,
                                unsigned short* __restrict__ BF,
                                int N, float* gO, float* gL) {
  int idx = blockIdx.x * 256 + threadIdx.x;
  int j = idx & 7;
  int l = (idx >> 3) & 63;
  int rest = idx >> 9;            // ks*NT + nt
  int NT = N >> 4;
  int nt = rest % NT, ks = rest / NT;
  int k = ks * 32 + ((l >> 4) << 3) + j;
  int n = (nt << 4) + (l & 15);
  BF[idx] = f2bf(B[(size_t)k * N + n]);
  if (gO && idx < BATCH * UNITS) gO[idx] = 0.0f;
  if (gL && idx < BATCH)         gL[idx] = 0.0f;
}

// ---------------------------------------------------------------------------
// mm64: C[64 x n-slab(128)] = A[64 x K] @ B[K x N] (+b1)(+b2), optional A-row
// scale 1/denom[m]. A staged once to LDS bf16 (persistent), k-loop barrier-free,
// B from frag-order bf16 (L2-hot). grid.x = n-slabs of 128. 256 thr = 4 waves.
// dyn LDS = 64*(K+8)*2 bytes.
// ---------------------------------------------------------------------------
__launch_bounds__(256, 2)
__global__ void mm64_kernel(const float* __restrict__ A, int lda,
                            const unsigned short* __restrict__ BF, int NT, int nt0,
                            const float* __restrict__ b1,
                            const float* __restrict__ b2,
                            const float* __restrict__ denom,
                            float* __restrict__ out, int ldo, int K) {
  extern __shared__ unsigned short At[];     // [64][K+8]
  const int tid = threadIdx.x;
  const int lane = tid & 63, w = tid >> 6;
  const int row_a = lane & 15, kq = lane >> 4;
  const int ldA = K + 8;

  // ---- stage A (64 x K f32) -> bf16 LDS, optional per-row scale ----
  const int f4pr = K >> 2;                   // float4s per row
  for (int i = tid; i < 64 * f4pr; i += 256) {
    int row = i / f4pr, c4 = i - row * f4pr;
    float sc = 1.0f;
    if (denom) sc = __fdividef(1.0f, denom[row]);
    float4 v = *(const float4*)(A + (size_t)row * lda + c4 * 4);
    ushort4 q = make_ushort4(f2bf(v.x * sc), f2bf(v.y * sc), f2bf(v.z * sc), f2bf(v.w * sc));
    *(ushort4*)&At[row * ldA + c4 * 4] = q;
  }
  __syncthreads();

  f32x4 acc[4][2];
#pragma unroll
  for (int mt = 0; mt < 4; ++mt)
#pragma unroll
    for (int ntl = 0; ntl < 2; ++ntl)
      acc[mt][ntl] = (f32x4){0.0f, 0.0f, 0.0f, 0.0f};

  const int ntf0 = nt0 + blockIdx.x * 8 + w * 2;
  const int KS = K >> 5;
  for (int ks = 0; ks < KS; ++ks) {
    bf16x8 af[4];
#pragma unroll
    for (int mt = 0; mt < 4; ++mt)
      af[mt] = *(const bf16x8*)&At[(mt * 16 + row_a) * ldA + ks * 32 + kq * 8];
#pragma unroll
    for (int ntl = 0; ntl < 2; ++ntl) {
      bf16x8 bfr = *(const bf16x8*)(BF + (((size_t)ks * NT + ntf0 + ntl) * 64 + lane) * 8);
#pragma unroll
      for (int mt = 0; mt < 4; ++mt)
        acc[mt][ntl] = __builtin_amdgcn_mfma_f32_16x16x32_bf16(af[mt], bfr, acc[mt][ntl], 0, 0, 0);
    }
  }

  // ---- epilogue: C/D layout col = row_a, row = kq*4 + r ----
#pragma unroll
  for (int ntl = 0; ntl < 2; ++ntl) {
    int col = blockIdx.x * 128 + w * 32 + ntl * 16 + row_a;
    float bb = 0.0f;
    if (b1) bb += b1[col];
    if (b2) bb += b2[col];
#pragma unroll
    for (int mt = 0; mt < 4; ++mt)
#pragma unroll
      for (int r = 0; r < 4; ++r) {
        int row = mt * 16 + kq * 4 + r;
        out[(size_t)row * ldo + col] = acc[mt][ntl][r] + bb;
      }
  }
}

// ---------------------------------------------------------------------------
// score_ctx: fused attention score + softmax partials + weighted context sum.
// Block = (b, 64 t-rows), full N=512. A-tile persistent in LDS bf16 (64 KB),
// ONE barrier before the k-loop; k-loop fully unrolled, barrier-free; B frags
// streamed from L2. Epilogue re-reads the LDS tile (not global).
// ---------------------------------------------------------------------------
__launch_bounds__(256, 2)
__global__ void score_ctx_kernel(const float* __restrict__ ctx,
                                 const unsigned short* __restrict__ WaF,
                                 const float* __restrict__ uvec,
                                 const float* __restrict__ Va,
                                 float* __restrict__ gO,
                                 float* __restrict__ gL) {
  __shared__ unsigned short At[64][520];   // 64 rows x (512 + 8 pad) bf16 = 66.5 KB
  __shared__ float sS[64];
  __shared__ float sE[64];

  const int b   = blockIdx.y;
  const int tc  = blockIdx.x;
  const int tid = threadIdx.x;
  const int lane  = tid & 63;
  const int w     = tid >> 6;
  const int row_a = lane & 15;
  const int kq    = lane >> 4;

  const float* ctile = ctx + ((size_t)b * TLEN + (size_t)tc * 64) * UNITS;
  if (tid < 64) sS[tid] = 0.0f;

  // ---- stage whole tile: 8192 float4s, perfectly coalesced ----
  const float4* src = (const float4*)ctile;
#pragma unroll
  for (int i = 0; i < 32; ++i) {
    int f4 = i * 256 + tid;
    int row = f4 >> 7, c4 = f4 & 127;
    float4 v = src[f4];
    ushort4 q = make_ushort4(f2bf(v.x), f2bf(v.y), f2bf(v.z), f2bf(v.w));
    *(ushort4*)&At[row][c4 * 4] = q;
  }
  __syncthreads();

  f32x4 acc[4][8];
#pragma unroll
  for (int mt = 0; mt < 4; ++mt)
#pragma unroll
    for (int nt = 0; nt < 8; ++nt)
      acc[mt][nt] = (f32x4){0.0f, 0.0f, 0.0f, 0.0f};

#pragma unroll
  for (int ks = 0; ks < 16; ++ks) {
    bf16x8 af[4];
#pragma unroll
    for (int mt = 0; mt < 4; ++mt)
      af[mt] = *(const bf16x8*)&At[mt * 16 + row_a][ks * 32 + kq * 8];
#pragma unroll
    for (int nt = 0; nt < 8; ++nt) {
      bf16x8 bfr = *(const bf16x8*)(WaF + (((size_t)ks * 32 + (w << 3) + nt) * 64 + lane) * 8);
#pragma unroll
      for (int mt = 0; mt < 4; ++mt)
        acc[mt][nt] = __builtin_amdgcn_mfma_f32_16x16x32_bf16(af[mt], bfr, acc[mt][nt], 0, 0, 0);
    }
  }

  // ---- s_t = sum_n tanh(y + u) * Va ----
  float uvals[8], vvals[8];
#pragma unroll
  for (int nt = 0; nt < 8; ++nt) {
    int n_g = (w << 7) + (nt << 4) + row_a;
    uvals[nt] = uvec[b * UNITS + n_g];
    vvals[nt] = Va[n_g];
  }
#pragma unroll
  for (int mt = 0; mt < 4; ++mt) {
#pragma unroll
    for (int r = 0; r < 4; ++r) {
      float v = 0.0f;
#pragma unroll
      for (int nt = 0; nt < 8; ++nt)
        v += fast_tanh(acc[mt][nt][r] + uvals[nt]) * vvals[nt];
      v += __shfl_xor(v, 1);
      v += __shfl_xor(v, 2);
      v += __shfl_xor(v, 4);
      v += __shfl_xor(v, 8);
      if (row_a == 0) atomicAdd(&sS[mt * 16 + kq * 4 + r], v);
    }
  }
  __syncthreads();
  if (tid < 64) sE[tid] = __expf(sS[tid]);
  __syncthreads();
  if (tid < 64) {
    float e = sE[tid];
#pragma unroll
    for (int off = 1; off < 64; off <<= 1) e += __shfl_xor(e, off);
    if (tid == 0) atomicAdd(&gL[b], e);
  }
  // ---- weighted context sum from the LDS tile (bf16) ----
  {
    float o0 = 0.0f, o1 = 0.0f;
#pragma unroll 8
    for (int t = 0; t < 64; ++t) {
      unsigned u = *(const unsigned*)&At[t][tid * 2];
      float e = sE[t];
      o0 = fmaf(e, bf2f((unsigned short)(u & 0xffff)), o0);
      o1 = fmaf(e, bf2f((unsigned short)(u >> 16)), o1);
    }
    atomicAdd(&gO[b * UNITS + tid * 2], o0);
    atomicAdd(&gO[b * UNITS + tid * 2 + 1], o1);
  }
}

// ---------------------------------------------------------------------------
__global__ void gates_kernel(const float* __restrict__ xg,
                             const float* __restrict__ rec_zr,
                             const float* __restrict__ cg,
                             const float* __restrict__ h,
                             float* __restrict__ zbuf,
                             float* __restrict__ rhbuf) {
  int idx = blockIdx.x * 256 + threadIdx.x;   // 64*512
  int m = idx >> 9, j = idx & 511;
  float xz = xg[m * 1536 + j],        xr = xg[m * 1536 + 512 + j];
  float rz = rec_zr[m * 1024 + j],    rr = rec_zr[m * 1024 + 512 + j];
  float cz = cg[m * 1536 + j],        cr = cg[m * 1536 + 512 + j];
  float z = fast_sigmoid(xz + rz + cz);
  float r = fast_sigmoid(xr + rr + cr);
  zbuf[idx]  = z;
  rhbuf[idx] = r * h[idx];
}

__global__ void newh_kernel(const float* __restrict__ xg,
                            const float* __restrict__ rech,
                            const float* __restrict__ cg,
                            const float* __restrict__ zbuf,
                            const float* __restrict__ h,
                            float* __restrict__ hout) {
  int idx = blockIdx.x * 256 + threadIdx.x;
  int m = idx >> 9, j = idx & 511;
  float hb = fast_tanh(xg[m * 1536 + 1024 + j] + rech[idx] + cg[m * 1536 + 1024 + j]);
  float z  = zbuf[idx];
  hout[idx] = z * h[idx] + (1.0f - z) * hb;
}

// ---------------------------------------------------------------------------
extern "C" void kernel_launch(void* const* d_in, const int* in_sizes, int n_in,
                              void* d_out, int out_size, void* d_ws, size_t ws_size,
                              hipStream_t stream) {
  (void)in_sizes; (void)n_in; (void)out_size; (void)ws_size;
  const float* inputs = (const float*)d_in[0];
  const float* h_tm1  = (const float*)d_in[1];
  const float* ctx    = (const float*)d_in[2];
  const float* Wi     = (const float*)d_in[3];
  const float* bi     = (const float*)d_in[4];
  const float* kern   = (const float*)d_in[5];
  const float* rk     = (const float*)d_in[6];
  const float* ak     = (const float*)d_in[7];
  const float* bias   = (const float*)d_in[8];
  const float* Wa     = (const float*)d_in[9];
  const float* ba_w   = (const float*)d_in[10];
  const float* Ua     = (const float*)d_in[11];
  const float* ba_u   = (const float*)d_in[12];
  const float* Va     = (const float*)d_in[13];
  // d_in[14] = ba_v: unused (softmax shift-invariance)
  const float* Wo     = (const float*)d_in[15];
  const float* bo     = (const float*)d_in[16];

  float* out = (float*)d_out;               // [64][512] out, then [64][512] h
  float* h_new = out + BATCH * UNITS;
  float* ws  = (float*)d_ws;

  // frag-order bf16 weight buffers (float-unit offsets)
  unsigned short* WaF   = (unsigned short*)(ws);             // 262144 bf16
  unsigned short* WiF   = (unsigned short*)(ws + 131072);    // 131072 bf16
  unsigned short* kernF = (unsigned short*)(ws + 196608);    // 786432 bf16
  unsigned short* UaF   = (unsigned short*)(ws + 589824);    // 262144 bf16
  unsigned short* rkF   = (unsigned short*)(ws + 720896);    // 786432 bf16
  unsigned short* akF   = (unsigned short*)(ws + 1114112);   // 786432 bf16
  unsigned short* WoF   = (unsigned short*)(ws + 1507328);   // 262144 bf16
  float* gO     = ws + 1638400;   // [64][512]
  float* gL     = ws + 1671168;   // [64]
  float* xbuf   = ws + 1671232;   // [64][512]
  float* xg     = ws + 1704000;   // [64][1536]
  float* ubuf   = ws + 1802304;   // [64][512]
  float* rec_zr = ws + 1835072;   // [64][1024]
  float* cg     = ws + 1900608;   // [64][1536]
  float* zbuf   = ws + 1998912;   // [64][512]
  float* rhbuf  = ws + 2031680;   // [64][512]
  float* rech   = ws + 2064448;   // [64][512]

  const size_t lds512 = 64 * (512 + 8) * sizeof(unsigned short);  // 66560
  const size_t lds256 = 64 * (256 + 8) * sizeof(unsigned short);  // 33792

  // ---- prep: weight relayouts (frag order bf16); zero gO/gL on first ----
  relayout_kernel<<<1024, 256, 0, stream>>>(Wa,   WaF,   512, gO, gL);
  relayout_kernel<<<512,  256, 0, stream>>>(Wi,   WiF,   512, nullptr, nullptr);
  relayout_kernel<<<3072, 256, 0, stream>>>(kern, kernF, 1536, nullptr, nullptr);
  relayout_kernel<<<1024, 256, 0, stream>>>(Ua,   UaF,   512, nullptr, nullptr);
  relayout_kernel<<<3072, 256, 0, stream>>>(rk,   rkF,   1536, nullptr, nullptr);
  relayout_kernel<<<3072, 256, 0, stream>>>(ak,   akF,   1536, nullptr, nullptr);
  relayout_kernel<<<1024, 256, 0, stream>>>(Wo,   WoF,   512, nullptr, nullptr);

  // x = inputs @ Wi + bi             (K=256, N=512)
  mm64_kernel<<<4, 256, lds256, stream>>>(inputs, EMBD, WiF, 32, 0, bi, nullptr, nullptr, xbuf, UNITS, EMBD);
  // xg = x @ kernel + bias           (K=512, N=1536)
  mm64_kernel<<<12, 256, lds512, stream>>>(xbuf, UNITS, kernF, 96, 0, bias, nullptr, nullptr, xg, 1536, UNITS);
  // u = h @ Ua + ba_u + ba_w         (K=512, N=512)
  mm64_kernel<<<4, 256, lds512, stream>>>(h_tm1, UNITS, UaF, 32, 0, ba_u, ba_w, nullptr, ubuf, UNITS, UNITS);
  // rec_z|rec_r = h @ rk[:, :1024]   (K=512, N=1024 of 1536)
  mm64_kernel<<<8, 256, lds512, stream>>>(h_tm1, UNITS, rkF, 96, 0, nullptr, nullptr, nullptr, rec_zr, 1024, UNITS);
  // fused attention
  score_ctx_kernel<<<dim3(32, 64), 256, 0, stream>>>(ctx, WaF, ubuf, Va, gO, gL);
  // cg = (gO/gL) @ attention_kernel  (K=512, N=1536)
  mm64_kernel<<<12, 256, lds512, stream>>>(gO, UNITS, akF, 96, 0, nullptr, nullptr, gL, cg, 1536, UNITS);
  // gates
  gates_kernel<<<128, 256, 0, stream>>>(xg, rec_zr, cg, h_tm1, zbuf, rhbuf);
  // rec_h = (r*h) @ rk[:, 1024:]     (K=512, N=512 of 1536, nt0=64)
  mm64_kernel<<<4, 256, lds512, stream>>>(rhbuf, UNITS, rkF, 96, 64, nullptr, nullptr, nullptr, rech, UNITS, UNITS);
  // h
  newh_kernel<<<128, 256, 0, stream>>>(xg, rech, cg, zbuf, h_tm1, h_new);
  // out = h @ Wo + bo
  mm64_kernel<<<4, 256, lds512, stream>>>(h_new, UNITS, WoF, 32, 0, bo, nullptr, nullptr, out, UNITS, UNITS);
}

// Round 4
// 616.601 us; speedup vs baseline: 1.0739x; 1.0739x over previous
//
#include <hip/hip_runtime.h>

#define UNITS 512
#define EMBD  256
#define BATCH 64
#define TLEN  2048

typedef __bf16 bf16x8 __attribute__((ext_vector_type(8)));
typedef float  f32x4  __attribute__((ext_vector_type(4)));

__device__ __forceinline__ unsigned short f2bf(float x) {
  return __builtin_bit_cast(unsigned short, (__bf16)x);
}
__device__ __forceinline__ float bf2f(unsigned short u) {
  unsigned v = ((unsigned)u) << 16;
  return __builtin_bit_cast(float, v);
}
__device__ __forceinline__ float fast_tanh(float x) {
  float e = __expf(2.0f * x);
  return __fdividef(e - 1.0f, e + 1.0f);
}
__device__ __forceinline__ float fast_sigmoid(float x) {
  return __fdividef(1.0f, 1.0f + __expf(-x));
}

// ---------------------------------------------------------------------------
// relayout_all: all 7 weight matrices -> MFMA B-fragment order bf16 in ONE
// launch. Source reads coalesced (idx enumerates source linearly); writes
// scattered 2B (fire-and-forget). Also zeros gO/gL.
//   dst[((ks*NT + nt)*64 + q*16 + (n&15))*8 + (k&7)], ks=k>>5, q=(k>>3)&3
// ---------------------------------------------------------------------------
struct R7 {
  const float* src[7];
  unsigned short* dst[7];
  int N[7];
  int end[7];   // cumulative block ends
};

__global__ void relayout_all_kernel(R7 r, float* __restrict__ gO,
                                    float* __restrict__ gL) {
  int bx = blockIdx.x;
  int gid = bx * 256 + threadIdx.x;
  if (gid < BATCH * UNITS) gO[gid] = 0.0f;
  if (gid < BATCH)         gL[gid] = 0.0f;
  int j = 0, start = 0;
#pragma unroll
  for (int t = 0; t < 7; ++t) {
    if (bx >= r.end[t]) { start = r.end[t]; j = t + 1; }
  }
  int idx = (bx - start) * 256 + threadIdx.x;
  int N = r.N[j];
  int k = (unsigned)idx / (unsigned)N;
  int n = idx - k * N;
  float v = r.src[j][idx];
  int NT = N >> 4;
  int ks = k >> 5, q = (k >> 3) & 3, j8 = k & 7;
  int dst = ((ks * NT + (n >> 4)) * 64 + q * 16 + (n & 15)) * 8 + j8;
  r.dst[j][dst] = f2bf(v);
}

// ---------------------------------------------------------------------------
// mm64 batched: C[64 x 128-col slab] = A[64 x K] @ B (+biases / fused epilog).
// A staged once to LDS bf16, barrier-free k-loop, B frag-order from L2.
// mode 0: plain (+b1+b2).  mode 1: cg->gates fused.  mode 2: rech->newh fused.
// ---------------------------------------------------------------------------
struct MMJob {
  const float* A; const unsigned short* BF;
  const float* b1; const float* b2; const float* denom;
  float* out;
  const float* p1; const float* p2; const float* p3;
  float* p4; float* p5;
  int lda, NT, nt0, ldo, K, nblk, mode;
};

__device__ __forceinline__ void mm_body(const MMJob& jb, int bx) {
  extern __shared__ unsigned short At[];     // [64][K+8]
  const int tid = threadIdx.x;
  const int lane = tid & 63, w = tid >> 6;
  const int row_a = lane & 15, kq = lane >> 4;
  const int K = jb.K;
  const int ldA = K + 8;

  const int f4pr = K >> 2;
  for (int i = tid; i < 64 * f4pr; i += 256) {
    int row = i / f4pr, c4 = i - row * f4pr;
    float sc = 1.0f;
    if (jb.denom) sc = __fdividef(1.0f, jb.denom[row]);
    float4 v = *(const float4*)(jb.A + (size_t)row * jb.lda + c4 * 4);
    ushort4 q = make_ushort4(f2bf(v.x * sc), f2bf(v.y * sc), f2bf(v.z * sc), f2bf(v.w * sc));
    *(ushort4*)&At[row * ldA + c4 * 4] = q;
  }
  __syncthreads();

  f32x4 acc[4][2];
#pragma unroll
  for (int mt = 0; mt < 4; ++mt)
#pragma unroll
    for (int ntl = 0; ntl < 2; ++ntl)
      acc[mt][ntl] = (f32x4){0.0f, 0.0f, 0.0f, 0.0f};

  const int ntf0 = jb.nt0 + bx * 8 + w * 2;
  const int KS = K >> 5;
  for (int ks = 0; ks < KS; ++ks) {
    bf16x8 af[4];
#pragma unroll
    for (int mt = 0; mt < 4; ++mt)
      af[mt] = *(const bf16x8*)&At[(mt * 16 + row_a) * ldA + ks * 32 + kq * 8];
#pragma unroll
    for (int ntl = 0; ntl < 2; ++ntl) {
      bf16x8 bfr = *(const bf16x8*)(jb.BF + (((size_t)ks * jb.NT + ntf0 + ntl) * 64 + lane) * 8);
#pragma unroll
      for (int mt = 0; mt < 4; ++mt)
        acc[mt][ntl] = __builtin_amdgcn_mfma_f32_16x16x32_bf16(af[mt], bfr, acc[mt][ntl], 0, 0, 0);
    }
  }

#pragma unroll
  for (int ntl = 0; ntl < 2; ++ntl) {
    int col = bx * 128 + w * 32 + ntl * 16 + row_a;
#pragma unroll
    for (int mt = 0; mt < 4; ++mt)
#pragma unroll
      for (int r = 0; r < 4; ++r) {
        int row = mt * 16 + kq * 4 + r;
        float a = acc[mt][ntl][r];
        if (jb.mode == 0) {
          if (jb.b1) a += jb.b1[col];
          if (jb.b2) a += jb.b2[col];
          jb.out[(size_t)row * jb.ldo + col] = a;
        } else if (jb.mode == 1) {
          // cg epilogue: p1=xg, p2=rec_zr, p3=h_tm1, out=zbuf, p4=rhbuf, p5=shbuf
          if (col < 512) {
            float v = a + jb.p1[row * 1536 + col] + jb.p2[row * 1024 + col];
            jb.out[row * 512 + col] = fast_sigmoid(v);
          } else if (col < 1024) {
            float v = a + jb.p1[row * 1536 + col] + jb.p2[row * 1024 + col];
            int c = col - 512;
            jb.p4[row * 512 + c] = fast_sigmoid(v) * jb.p3[row * 512 + c];
          } else {
            int c = col - 1024;
            jb.p5[row * 512 + c] = a + jb.p1[row * 1536 + col];
          }
        } else {
          // mode 2: rech epilogue: p1=zbuf, p2=h_tm1, p3=shbuf, out=h_new
          float hb = fast_tanh(a + jb.p3[row * 512 + col]);
          float z  = jb.p1[row * 512 + col];
          jb.out[row * 512 + col] = z * jb.p2[row * 512 + col] + (1.0f - z) * hb;
        }
      }
  }
}

__launch_bounds__(256, 2)
__global__ void mmbatch_kernel(MMJob j0, MMJob j1, MMJob j2) {
  int bx = blockIdx.x;
  if (bx < j0.nblk) { mm_body(j0, bx); return; }
  bx -= j0.nblk;
  if (bx < j1.nblk) { mm_body(j1, bx); return; }
  bx -= j1.nblk;
  mm_body(j2, bx);
}

// ---------------------------------------------------------------------------
// score_ctx: fused attention score + softmax partials + weighted context sum.
// Block = 512 threads (8 waves) on a (b, 64-row) tile; wave w covers nt
// w*4..w*4+3 -> acc[4][4] = 64 regs/wave, total <=128 -> 16 waves/CU
// (2 blocks x 8 waves; LDS 66.5 KB caps blocks at 2). Barrier-free k-loop.
// ---------------------------------------------------------------------------
__launch_bounds__(512, 4)
__global__ void score_ctx_kernel(const float* __restrict__ ctx,
                                 const unsigned short* __restrict__ WaF,
                                 const float* __restrict__ uvec,
                                 const float* __restrict__ Va,
                                 float* __restrict__ gO,
                                 float* __restrict__ gL) {
  __shared__ unsigned short At[64][520];   // 66560 B
  __shared__ float sS[64];
  __shared__ float sE[64];

  const int b   = blockIdx.y;
  const int tc  = blockIdx.x;
  const int tid = threadIdx.x;
  const int lane  = tid & 63;
  const int w     = tid >> 6;       // 0..7
  const int row_a = lane & 15;
  const int kq    = lane >> 4;

  const float* ctile = ctx + ((size_t)b * TLEN + (size_t)tc * 64) * UNITS;
  if (tid < 64) sS[tid] = 0.0f;

  // stage whole tile: 8192 float4s over 512 threads
  const float4* src = (const float4*)ctile;
#pragma unroll
  for (int i = 0; i < 16; ++i) {
    int f4 = i * 512 + tid;
    int row = f4 >> 7, c4 = f4 & 127;
    float4 v = src[f4];
    ushort4 q = make_ushort4(f2bf(v.x), f2bf(v.y), f2bf(v.z), f2bf(v.w));
    *(ushort4*)&At[row][c4 * 4] = q;
  }
  __syncthreads();

  f32x4 acc[4][4];
#pragma unroll
  for (int mt = 0; mt < 4; ++mt)
#pragma unroll
    for (int ntl = 0; ntl < 4; ++ntl)
      acc[mt][ntl] = (f32x4){0.0f, 0.0f, 0.0f, 0.0f};

#pragma unroll 4
  for (int ks = 0; ks < 16; ++ks) {
    bf16x8 af[4];
#pragma unroll
    for (int mt = 0; mt < 4; ++mt)
      af[mt] = *(const bf16x8*)&At[mt * 16 + row_a][ks * 32 + kq * 8];
#pragma unroll
    for (int ntl = 0; ntl < 4; ++ntl) {
      bf16x8 bfr = *(const bf16x8*)(WaF + (((size_t)ks * 32 + (w << 2) + ntl) * 64 + lane) * 8);
#pragma unroll
      for (int mt = 0; mt < 4; ++mt)
        acc[mt][ntl] = __builtin_amdgcn_mfma_f32_16x16x32_bf16(af[mt], bfr, acc[mt][ntl], 0, 0, 0);
    }
  }

  // s_t partial = sum_n tanh(y + u) * Va over this wave's 64 n-cols
  float uvals[4], vvals[4];
#pragma unroll
  for (int ntl = 0; ntl < 4; ++ntl) {
    int n_g = ((w << 2) + ntl) * 16 + row_a;
    uvals[ntl] = uvec[b * UNITS + n_g];
    vvals[ntl] = Va[n_g];
  }
#pragma unroll
  for (int mt = 0; mt < 4; ++mt) {
#pragma unroll
    for (int r = 0; r < 4; ++r) {
      float v = 0.0f;
#pragma unroll
      for (int ntl = 0; ntl < 4; ++ntl)
        v += fast_tanh(acc[mt][ntl][r] + uvals[ntl]) * vvals[ntl];
      v += __shfl_xor(v, 1);
      v += __shfl_xor(v, 2);
      v += __shfl_xor(v, 4);
      v += __shfl_xor(v, 8);
      if (row_a == 0) atomicAdd(&sS[mt * 16 + kq * 4 + r], v);
    }
  }
  __syncthreads();
  if (tid < 64) sE[tid] = __expf(sS[tid]);
  __syncthreads();
  if (tid < 64) {
    float e = sE[tid];
#pragma unroll
    for (int off = 1; off < 64; off <<= 1) e += __shfl_xor(e, off);
    if (tid == 0) atomicAdd(&gL[b], e);
  }
  // weighted context sum from LDS tile: thread tid owns column tid
  {
    float o = 0.0f;
#pragma unroll 8
    for (int t = 0; t < 64; ++t)
      o = fmaf(sE[t], bf2f(At[t][tid]), o);
    atomicAdd(&gO[b * UNITS + tid], o);
  }
}

// ---------------------------------------------------------------------------
extern "C" void kernel_launch(void* const* d_in, const int* in_sizes, int n_in,
                              void* d_out, int out_size, void* d_ws, size_t ws_size,
                              hipStream_t stream) {
  (void)in_sizes; (void)n_in; (void)out_size; (void)ws_size;
  const float* inputs = (const float*)d_in[0];
  const float* h_tm1  = (const float*)d_in[1];
  const float* ctx    = (const float*)d_in[2];
  const float* Wi     = (const float*)d_in[3];
  const float* bi     = (const float*)d_in[4];
  const float* kern   = (const float*)d_in[5];
  const float* rk     = (const float*)d_in[6];
  const float* ak     = (const float*)d_in[7];
  const float* bias   = (const float*)d_in[8];
  const float* Wa     = (const float*)d_in[9];
  const float* ba_w   = (const float*)d_in[10];
  const float* Ua     = (const float*)d_in[11];
  const float* ba_u   = (const float*)d_in[12];
  const float* Va     = (const float*)d_in[13];
  // d_in[14] = ba_v: unused (softmax shift-invariance)
  const float* Wo     = (const float*)d_in[15];
  const float* bo     = (const float*)d_in[16];

  float* out = (float*)d_out;               // [64][512] out, then [64][512] h
  float* h_new = out + BATCH * UNITS;
  float* ws  = (float*)d_ws;

  unsigned short* WaF   = (unsigned short*)(ws);             // 262144 bf16
  unsigned short* WiF   = (unsigned short*)(ws + 131072);    // 131072 bf16
  unsigned short* kernF = (unsigned short*)(ws + 196608);    // 786432 bf16
  unsigned short* UaF   = (unsigned short*)(ws + 589824);    // 262144 bf16
  unsigned short* rkF   = (unsigned short*)(ws + 720896);    // 786432 bf16
  unsigned short* akF   = (unsigned short*)(ws + 1114112);   // 786432 bf16
  unsigned short* WoF   = (unsigned short*)(ws + 1507328);   // 262144 bf16
  float* gO     = ws + 1638400;   // [64][512]
  float* gL     = ws + 1671168;   // [64]
  float* xbuf   = ws + 1671232;   // [64][512]
  float* xg     = ws + 1704000;   // [64][1536]
  float* ubuf   = ws + 1802304;   // [64][512]
  float* rec_zr = ws + 1835072;   // [64][1024]
  float* zbuf   = ws + 1998912;   // [64][512]
  float* rhbuf  = ws + 2031680;   // [64][512]
  float* shbuf  = ws + 2064448;   // [64][512]  (x_h + c_h)

  const size_t lds512 = 64 * (512 + 8) * sizeof(unsigned short);  // 66560

  // ---- L1: all weight relayouts + zero accumulators (one launch) ----
  R7 r;
  r.src[0] = Wa;   r.dst[0] = WaF;   r.N[0] = 512;  r.end[0] = 1024;
  r.src[1] = Wi;   r.dst[1] = WiF;   r.N[1] = 512;  r.end[1] = 1536;
  r.src[2] = kern; r.dst[2] = kernF; r.N[2] = 1536; r.end[2] = 4608;
  r.src[3] = Ua;   r.dst[3] = UaF;   r.N[3] = 512;  r.end[3] = 5632;
  r.src[4] = rk;   r.dst[4] = rkF;   r.N[4] = 1536; r.end[4] = 8704;
  r.src[5] = ak;   r.dst[5] = akF;   r.N[5] = 1536; r.end[5] = 11776;
  r.src[6] = Wo;   r.dst[6] = WoF;   r.N[6] = 512;  r.end[6] = 12800;
  relayout_all_kernel<<<12800, 256, 0, stream>>>(r, gO, gL);

  MMJob jz{}; jz.nblk = 0;

  // ---- L2: independent pre-GEMMs {x, u, rec_zr} ----
  MMJob jx{};  jx.A = inputs; jx.lda = EMBD;  jx.BF = WiF; jx.NT = 32; jx.nt0 = 0;
  jx.b1 = bi;  jx.out = xbuf; jx.ldo = UNITS; jx.K = EMBD; jx.nblk = 4; jx.mode = 0;
  MMJob ju{};  ju.A = h_tm1; ju.lda = UNITS; ju.BF = UaF; ju.NT = 32; ju.nt0 = 0;
  ju.b1 = ba_u; ju.b2 = ba_w; ju.out = ubuf; ju.ldo = UNITS; ju.K = UNITS; ju.nblk = 4; ju.mode = 0;
  MMJob jr{};  jr.A = h_tm1; jr.lda = UNITS; jr.BF = rkF; jr.NT = 96; jr.nt0 = 0;
  jr.out = rec_zr; jr.ldo = 1024; jr.K = UNITS; jr.nblk = 8; jr.mode = 0;
  mmbatch_kernel<<<16, 256, lds512, stream>>>(jx, ju, jr);

  // ---- L3: xg = x @ kernel + bias ----
  MMJob jxg{}; jxg.A = xbuf; jxg.lda = UNITS; jxg.BF = kernF; jxg.NT = 96; jxg.nt0 = 0;
  jxg.b1 = bias; jxg.out = xg; jxg.ldo = 1536; jxg.K = UNITS; jxg.nblk = 12; jxg.mode = 0;
  mmbatch_kernel<<<12, 256, lds512, stream>>>(jxg, jz, jz);

  // ---- L4: fused attention ----
  score_ctx_kernel<<<dim3(32, 64), 512, 0, stream>>>(ctx, WaF, ubuf, Va, gO, gL);

  // ---- L5: cg = (gO/gL) @ ak, fused gates epilogue ----
  MMJob jcg{}; jcg.A = gO; jcg.lda = UNITS; jcg.BF = akF; jcg.NT = 96; jcg.nt0 = 0;
  jcg.denom = gL; jcg.K = UNITS; jcg.nblk = 12; jcg.mode = 1;
  jcg.out = zbuf; jcg.p1 = xg; jcg.p2 = rec_zr; jcg.p3 = h_tm1; jcg.p4 = rhbuf; jcg.p5 = shbuf;
  mmbatch_kernel<<<12, 256, lds512, stream>>>(jcg, jz, jz);

  // ---- L6: rech = rhbuf @ rk[:,1024:], fused newh epilogue -> h_new ----
  MMJob jrh{}; jrh.A = rhbuf; jrh.lda = UNITS; jrh.BF = rkF; jrh.NT = 96; jrh.nt0 = 64;
  jrh.K = UNITS; jrh.nblk = 4; jrh.mode = 2;
  jrh.out = h_new; jrh.p1 = zbuf; jrh.p2 = h_tm1; jrh.p3 = shbuf;
  mmbatch_kernel<<<4, 256, lds512, stream>>>(jrh, jz, jz);

  // ---- L7: out = h_new @ Wo + bo ----
  MMJob jo{}; jo.A = h_new; jo.lda = UNITS; jo.BF = WoF; jo.NT = 32; jo.nt0 = 0;
  jo.b1 = bo; jo.out = out; jo.ldo = UNITS; jo.K = UNITS; jo.nblk = 4; jo.mode = 0;
  mmbatch_kernel<<<4, 256, lds512, stream>>>(jo, jz, jz);
}